// Round 20
// baseline (437.224 us; speedup 1.0000x reference)
//
#include <hip/hip_runtime.h>
#include <hip/hip_bf16.h>
#include <math.h>

#define BB 8
#define HS 64
#define WS 64
#define LL 4096
#define DM 96
#define DI 192
#define NS 16
#define RR 6
#define KK 4
#define NCH 128
#define LC 32
#define XP 16
#define EPSN 1e-6f

typedef __attribute__((ext_vector_type(2))) float f32x2;

__device__ __forceinline__ float fsilu(float x) { return x / (1.f + __expf(-x)); }
// raw hardware transcendentals: v_exp_f32 computes 2^x, v_log_f32 computes log2(x)
__device__ __forceinline__ float rexp2(float x) {
    float r; asm("v_exp_f32 %0, %1" : "=v"(r) : "v"(x)); return r;
}
__device__ __forceinline__ float rlog2(float x) {
    float r; asm("v_log_f32 %0, %1" : "=v"(r) : "v"(x)); return r;
}
// packed f32 math (full-rate on CDNA): one instruction per 2 lanes-worth
__device__ __forceinline__ f32x2 pk_mul(f32x2 a, f32x2 b) {
    f32x2 d; asm("v_pk_mul_f32 %0, %1, %2" : "=v"(d) : "v"(a), "v"(b)); return d;
}
__device__ __forceinline__ f32x2 pk_fma(f32x2 a, f32x2 b, f32x2 c) {
    f32x2 d; asm("v_pk_fma_f32 %0, %1, %2, %3" : "=v"(d) : "v"(a), "v"(b), "v"(c)); return d;
}
// softplus(x) = ln(1+e^x) = ln2 * log2(1 + 2^(x*log2e))
__device__ __forceinline__ float fsoftplus(float x) {
    float t = rexp2(x * 1.44269504f);
    float r = 0.69314718f * rlog2(1.f + t);
    return (x > 20.f) ? x : r;
}
// spatial index l for direction k at scan step t; lmap is an involution per k,
// so it is also the scan step at which direction k visits spatial index l.
__device__ __forceinline__ int lmap(int k, int t) {
    int tt = (k >= 2) ? (LL - 1 - t) : t;
    if (k & 1) tt = ((tt & 63) << 6) | (tt >> 6);
    return tt;
}

// ---------------- K1: in_proj + silu(z) — 4 channels x 16 positions per thread ----------------
__global__ __launch_bounds__(192) void k_inproj(const float* __restrict__ x,
        const float* __restrict__ Win, float* __restrict__ xx, float* __restrict__ zs) {
    __shared__ __align__(16) float xrow[32][96];   // 12 KB
    int p0 = blockIdx.x * 32;
    int tid = threadIdx.x;
    {   // stage 32*96 floats = 768 float4, 4 per thread
        const float4* src = (const float4*)(x + (size_t)p0 * 96);
        float4* dst = (float4*)&xrow[0][0];
        #pragma unroll
        for (int e = 0; e < 4; ++e) dst[tid + e * 192] = src[tid + e * 192];
    }
    __syncthreads();
    int c = tid % 96;          // channel base: handles c, c+96 (->xx), c+192, c+288 (->z)
    int pg = tid / 96;         // position half: [pg*16, pg*16+16)
    const float4* w0 = (const float4*)(Win + (size_t)c * 96);
    const float4* w1 = (const float4*)(Win + (size_t)(c + 96) * 96);
    const float4* w2 = (const float4*)(Win + (size_t)(c + 192) * 96);
    const float4* w3 = (const float4*)(Win + (size_t)(c + 288) * 96);
    float a0v[16], a1v[16], a2v[16], a3v[16];
    #pragma unroll
    for (int p = 0; p < 16; ++p) { a0v[p] = 0.f; a1v[p] = 0.f; a2v[p] = 0.f; a3v[p] = 0.f; }
    for (int i = 0; i < 24; ++i) {
        float4 q0 = w0[i], q1 = w1[i], q2 = w2[i], q3 = w3[i];
        #pragma unroll
        for (int p = 0; p < 16; ++p) {
            float4 x4 = *(const float4*)&xrow[pg * 16 + p][i * 4];
            a0v[p] += q0.x * x4.x + q0.y * x4.y + q0.z * x4.z + q0.w * x4.w;
            a1v[p] += q1.x * x4.x + q1.y * x4.y + q1.z * x4.z + q1.w * x4.w;
            a2v[p] += q2.x * x4.x + q2.y * x4.y + q2.z * x4.z + q2.w * x4.w;
            a3v[p] += q3.x * x4.x + q3.y * x4.y + q3.z * x4.z + q3.w * x4.w;
        }
    }
    #pragma unroll
    for (int p = 0; p < 16; ++p) {
        size_t row = (size_t)(p0 + pg * 16 + p) * DI;
        xx[row + c]      = a0v[p];
        xx[row + c + 96] = a1v[p];
        zs[row + c]      = fsilu(a2v[p]);
        zs[row + c + 96] = fsilu(a3v[p]);
    }
}

// ---------------- K2: depthwise conv 3x3 + silu ----------------
__global__ __launch_bounds__(256) void k_conv(const float* __restrict__ xx,
        const float* __restrict__ cw, const float* __restrict__ cb,
        float* __restrict__ xc) {
    int idx = blockIdx.x * 256 + threadIdx.x;   // = P*192 + d
    int d = idx % DI; int P = idx / DI;
    int l = P & (LL - 1); int h = l >> 6; int w = l & 63;
    float acc = cb[d];
    #pragma unroll
    for (int i = 0; i < 3; ++i) {
        int hh = h + i - 1;
        if ((unsigned)hh < 64u) {
            #pragma unroll
            for (int j = 0; j < 3; ++j) {
                int ww = w + j - 1;
                if ((unsigned)ww < 64u)
                    acc += xx[(size_t)(P + (i - 1) * 64 + (j - 1)) * DI + d] * cw[d * 9 + i * 3 + j];
            }
        }
    }
    xc[idx] = fsilu(acc);
}

// ---------------- K3: x_dbl = xs @ xpw^T  -> dts_raw / Bs / Cs (scan order) ----------------
__global__ __launch_bounds__(192) void k_xdbl(const float* __restrict__ xc,
        const float* __restrict__ xpw, float* __restrict__ dts_raw,
        float* __restrict__ Bs, float* __restrict__ Cs) {
    __shared__ __align__(16) float xt[XP][DI];
    int tid = threadIdx.x;
    int p0 = blockIdx.x * XP;
    {
        const float4* src = (const float4*)(xc + (size_t)p0 * DI);
        float4* dst = (float4*)&xt[0][0];
        #pragma unroll
        for (int e = 0; e < XP * DI / 4 / 192; ++e) dst[tid + e * 192] = src[tid + e * 192];
    }
    __syncthreads();
    int c = tid;
    int k = c / 38, c2 = c % 38;
    const float4* w4p = (const float4*)(xpw + (size_t)c * DI);
    float acc[XP];
    #pragma unroll
    for (int p = 0; p < XP; ++p) acc[p] = 0.f;
    if (c < 152) {
        #pragma unroll 4
        for (int i = 0; i < DI / 4; ++i) {
            float4 w4 = w4p[i];
            #pragma unroll
            for (int p = 0; p < XP; ++p) {
                float4 x4 = *(const float4*)&xt[p][i * 4];
                acc[p] += w4.x * x4.x + w4.y * x4.y + w4.z * x4.z + w4.w * x4.w;
            }
        }
        #pragma unroll
        for (int p = 0; p < XP; ++p) {
            int P = p0 + p;
            int b = P >> 12; int l = P & (LL - 1);
            int lt = ((l & 63) << 6) | (l >> 6);
            int tk = (k == 0) ? l : (k == 1) ? lt : (k == 2) ? (LL - 1 - l) : (LL - 1 - lt);
            size_t it = ((size_t)(b * KK + k) * LL + tk);
            if (c2 < RR)            dts_raw[it * RR + c2] = acc[p];
            else if (c2 < RR + NS)  Bs[it * NS + (c2 - RR)] = acc[p];
            else                    Cs[it * NS + (c2 - RR - NS)] = acc[p];
        }
    }
}

// ---------------- K5a: chunked scan pass 1 — state-split: 384 threads, (d, nhalf) ----------------
// The 16 state recurrences are independent in pass 1 (no y-reduction), so splitting n across
// 2 thread-groups is communication-free: per-thread trans 16->8 exps/step, VALU ~halved,
// wave count doubled (2x latency-hiding pool). dt/softplus recomputed per half (cheap).
__global__ __launch_bounds__(384) void k_scan1(const float* __restrict__ xc,
        const float* __restrict__ dts_raw, const float* __restrict__ Bsg,
        const float* __restrict__ A_logs, const float* __restrict__ dtw,
        const float* __restrict__ dtb,
        float* __restrict__ asum_g, float* __restrict__ hpart) {
    __shared__ __align__(16) float dts_s[LC * 8];
    __shared__ __align__(16) float bs_s[LC * NS];
    int bi = blockIdx.x;
    int b = bi >> 9; int rem = bi & 511; int k = rem >> 7; int c0 = rem & 127;
    int t0 = c0 * LC;
    int tid = threadIdx.x;
    int d = tid % DI;          // channel
    int nh = tid / DI;         // state half: n in [nh*8, nh*8+8)
    size_t g0 = (size_t)(b * KK + k) * LL + t0;
    for (int e = tid; e < LC * RR; e += 384) dts_s[(e / RR) * 8 + (e % RR)] = dts_raw[g0 * RR + e];
    for (int e = tid; e < LC * NS; e += 384) bs_s[e] = Bsg[g0 * NS + e];
    __syncthreads();
    int kd = k * DI + d;
    f32x2 Ar2v[4];
    #pragma unroll
    for (int n2 = 0; n2 < 4; ++n2) {
        Ar2v[n2].x = -__expf(A_logs[(size_t)kd * NS + nh * 8 + 2 * n2]) * 1.44269504f;
        Ar2v[n2].y = -__expf(A_logs[(size_t)kd * NS + nh * 8 + 2 * n2 + 1]) * 1.44269504f;
    }
    f32x2 dw2[3];
    #pragma unroll
    for (int r = 0; r < 3; ++r) { dw2[r].x = dtw[kd * RR + 2 * r]; dw2[r].y = dtw[kd * RR + 2 * r + 1]; }
    float bias = dtb[kd];
    f32x2 h2[4];
    #pragma unroll
    for (int n2 = 0; n2 < 4; ++n2) h2[n2] = (f32x2){0.f, 0.f};
    float asum = 0.f;
    const float* xcb = xc + (size_t)b * LL * DI + d;
    float uu[4];
    #pragma unroll
    for (int j = 0; j < 4; ++j) uu[j] = xcb[(size_t)lmap(k, t0 + j) * DI];
    for (int tg = 0; tg < LC; tg += 4) {
        float un[4];
        int tb = t0 + ((tg + 4 < LC) ? (tg + 4) : tg);
        #pragma unroll
        for (int j = 0; j < 4; ++j) un[j] = xcb[(size_t)lmap(k, tb + j) * DI];
        #pragma unroll
        for (int j = 0; j < 4; ++j) {
            int t = tg + j;
            float4 q4 = *(const float4*)&dts_s[t * 8];
            float2 q2 = *(const float2*)&dts_s[t * 8 + 4];
            f32x2 a2 = pk_mul((f32x2){q4.x, q4.y}, dw2[0]);
            a2 = pk_fma((f32x2){q4.z, q4.w}, dw2[1], a2);
            a2 = pk_fma((f32x2){q2.x, q2.y}, dw2[2], a2);
            float dt = fsoftplus(bias + a2.x + a2.y);
            asum += dt;
            float dtu = dt * uu[j];
            f32x2 dt2 = {dt, dt}, dtu2 = {dtu, dtu};
            #pragma unroll
            for (int n4 = 0; n4 < 2; ++n4) {
                float4 b4 = *(const float4*)&bs_s[t * NS + nh * 8 + n4 * 4];
                f32x2 tl = pk_mul(dt2, Ar2v[n4 * 2]);
                f32x2 th = pk_mul(dt2, Ar2v[n4 * 2 + 1]);
                f32x2 el = {rexp2(tl.x), rexp2(tl.y)};
                f32x2 eh = {rexp2(th.x), rexp2(th.y)};
                h2[n4 * 2]     = pk_fma(h2[n4 * 2],     el, pk_mul(dtu2, (f32x2){b4.x, b4.y}));
                h2[n4 * 2 + 1] = pk_fma(h2[n4 * 2 + 1], eh, pk_mul(dtu2, (f32x2){b4.z, b4.w}));
            }
        }
        #pragma unroll
        for (int j = 0; j < 4; ++j) uu[j] = un[j];
    }
    if (nh == 0) asum_g[(size_t)bi * DI + d] = asum;
    size_t base = ((size_t)bi * DI + d) * NS + nh * 8;
    #pragma unroll
    for (int n4 = 0; n4 < 2; ++n4) {
        float4 hv = make_float4(h2[n4 * 2].x, h2[n4 * 2].y, h2[n4 * 2 + 1].x, h2[n4 * 2 + 1].y);
        *(float4*)&hpart[base + n4 * 4] = hv;
    }
}

// ---------------- K5b: propagate chunk-boundary states (in-place hpart -> hin) ----------------
// Unroll-8 with explicit batch prefetch (r19): loads are h-independent; prefetch hides L2 latency.
__global__ __launch_bounds__(256) void k_mid(const float* __restrict__ asum_g,
        const float* __restrict__ A_logs, float* __restrict__ hpp) {
    int g = blockIdx.x * 256 + threadIdx.x;   // B*K*DI*NS threads
    int bk = g / (DI * NS);
    int rem = g % (DI * NS);
    int d = rem >> 4; int n = rem & 15;
    int k = bk & 3;
    float Ar2 = -__expf(A_logs[(size_t)(k * DI + d) * NS + n]) * 1.44269504f;
    float h = 0.f;
    size_t rowbase = (size_t)bk * NCH * DI + d;
    float as[8], hp[8];
    #pragma unroll
    for (int j = 0; j < 8; ++j) {
        size_t row = rowbase + (size_t)j * DI;
        as[j] = asum_g[row];
        hp[j] = hpp[row * NS + n];
    }
    for (int c0 = 0; c0 < NCH; c0 += 8) {
        float asn[8], hpn[8];
        if (c0 + 8 < NCH) {
            #pragma unroll
            for (int j = 0; j < 8; ++j) {
                size_t row = rowbase + (size_t)(c0 + 8 + j) * DI;
                asn[j] = asum_g[row];
                hpn[j] = hpp[row * NS + n];
            }
        } else {
            #pragma unroll
            for (int j = 0; j < 8; ++j) { asn[j] = 0.f; hpn[j] = 0.f; }
        }
        #pragma unroll
        for (int j = 0; j < 8; ++j) {
            size_t row = rowbase + (size_t)(c0 + j) * DI;
            float a = rexp2(Ar2 * as[j]);
            hpp[row * NS + n] = h;      // becomes hin for chunk c0+j
            h = a * h + hp[j];
        }
        #pragma unroll
        for (int j = 0; j < 8; ++j) { as[j] = asn[j]; hp[j] = hpn[j]; }
    }
}

// ---------------- K5c: chunked scan pass 2 (LDS-staged; streaming per-direction y) ----------------
__global__ __launch_bounds__(192) void k_scan2(const float* __restrict__ xc,
        const float* __restrict__ dts_raw, const float* __restrict__ Bsg,
        const float* __restrict__ Csg, const float* __restrict__ A_logs,
        const float* __restrict__ dtw, const float* __restrict__ dtb,
        const float* __restrict__ hinb, float* __restrict__ ysb) {
    __shared__ __align__(16) float dts_s[LC * 8];
    __shared__ __align__(16) float bs_s[LC * NS];
    __shared__ __align__(16) float cs_s[LC * NS];
    int bi = blockIdx.x;
    int b = bi >> 9; int rem = bi & 511; int k = rem >> 7; int c0 = rem & 127;
    int t0 = c0 * LC;
    int d = threadIdx.x;
    size_t g0 = (size_t)(b * KK + k) * LL + t0;
    for (int e = d; e < LC * RR; e += DI) dts_s[(e / RR) * 8 + (e % RR)] = dts_raw[g0 * RR + e];
    for (int e = d; e < LC * NS; e += DI) bs_s[e] = Bsg[g0 * NS + e];
    for (int e = d; e < LC * NS; e += DI) cs_s[e] = Csg[g0 * NS + e];
    __syncthreads();
    int kd = k * DI + d;
    f32x2 Ar2v[8];
    #pragma unroll
    for (int n2 = 0; n2 < 8; ++n2) {
        Ar2v[n2].x = -__expf(A_logs[(size_t)kd * NS + 2 * n2]) * 1.44269504f;
        Ar2v[n2].y = -__expf(A_logs[(size_t)kd * NS + 2 * n2 + 1]) * 1.44269504f;
    }
    f32x2 dw2[3];
    #pragma unroll
    for (int r = 0; r < 3; ++r) { dw2[r].x = dtw[kd * RR + 2 * r]; dw2[r].y = dtw[kd * RR + 2 * r + 1]; }
    float bias = dtb[kd];
    size_t base = ((size_t)bi * DI + d) * NS;
    f32x2 h2[8];
    #pragma unroll
    for (int n4 = 0; n4 < 4; ++n4) {
        float4 hv = *(const float4*)&hinb[base + n4 * 4];
        h2[n4 * 2]     = (f32x2){hv.x, hv.y};
        h2[n4 * 2 + 1] = (f32x2){hv.z, hv.w};
    }
    const float* xcb = xc + (size_t)b * LL * DI + d;
    float* ysw = ysb + g0 * DI + d;   // per-direction output, SCAN order (coalesced)
    float uu[4];
    #pragma unroll
    for (int j = 0; j < 4; ++j) uu[j] = xcb[(size_t)lmap(k, t0 + j) * DI];
    for (int tg = 0; tg < LC; tg += 4) {
        float un[4];
        int tb = t0 + ((tg + 4 < LC) ? (tg + 4) : tg);
        #pragma unroll
        for (int j = 0; j < 4; ++j) un[j] = xcb[(size_t)lmap(k, tb + j) * DI];
        #pragma unroll
        for (int j = 0; j < 4; ++j) {
            int t = tg + j;
            float4 q4 = *(const float4*)&dts_s[t * 8];
            float2 q2 = *(const float2*)&dts_s[t * 8 + 4];
            f32x2 a2 = pk_mul((f32x2){q4.x, q4.y}, dw2[0]);
            a2 = pk_fma((f32x2){q4.z, q4.w}, dw2[1], a2);
            a2 = pk_fma((f32x2){q2.x, q2.y}, dw2[2], a2);
            float dt = fsoftplus(bias + a2.x + a2.y);
            float dtu = dt * uu[j];
            f32x2 dt2 = {dt, dt}, dtu2 = {dtu, dtu};
            f32x2 y2 = {0.f, 0.f};
            #pragma unroll
            for (int n4 = 0; n4 < 4; ++n4) {
                float4 b4 = *(const float4*)&bs_s[t * NS + n4 * 4];
                float4 c4 = *(const float4*)&cs_s[t * NS + n4 * 4];
                f32x2 tl = pk_mul(dt2, Ar2v[n4 * 2]);
                f32x2 th = pk_mul(dt2, Ar2v[n4 * 2 + 1]);
                f32x2 el = {rexp2(tl.x), rexp2(tl.y)};
                f32x2 eh = {rexp2(th.x), rexp2(th.y)};
                h2[n4 * 2]     = pk_fma(h2[n4 * 2],     el, pk_mul(dtu2, (f32x2){b4.x, b4.y}));
                h2[n4 * 2 + 1] = pk_fma(h2[n4 * 2 + 1], eh, pk_mul(dtu2, (f32x2){b4.z, b4.w}));
                y2 = pk_fma(h2[n4 * 2],     (f32x2){c4.x, c4.y}, y2);
                y2 = pk_fma(h2[n4 * 2 + 1], (f32x2){c4.z, c4.w}, y2);
            }
            ysw[(size_t)t * DI] = y2.x + y2.y;    // plain coalesced store, no atomics
        }
        #pragma unroll
        for (int j = 0; j < 4; ++j) uu[j] = un[j];
    }
}

// ---------------- K6: 4-way merge + D-skip + LayerNorm + gate + out_proj ----------------
__global__ __launch_bounds__(256) void k_final(const float* __restrict__ xc,
        const float* __restrict__ ysb, const float* __restrict__ Ds,
        const float* __restrict__ zs, const float* __restrict__ nw,
        const float* __restrict__ nb, const float* __restrict__ Wout,
        float* __restrict__ out) {
    __shared__ __align__(16) float gs[32][DI];
    int tid = threadIdx.x;
    int wv = tid >> 6, lane = tid & 63;
    int Pbase = blockIdx.x * 32;
    float nwv[3], nbv[3], sdv[3];
    #pragma unroll
    for (int j = 0; j < 3; ++j) {
        int c = lane + 64 * j;
        nwv[j] = nw[c]; nbv[j] = nb[c];
        sdv[j] = Ds[c] + Ds[DI + c] + Ds[2 * DI + c] + Ds[3 * DI + c];
    }
    for (int pi = 0; pi < 8; ++pi) {
        int pl = wv * 8 + pi;
        int P = Pbase + pl;
        int b = P >> 12, l = P & (LL - 1);
        size_t Poff = (size_t)P * DI;
        size_t r0 = ((size_t)(b * KK + 0) * LL + lmap(0, l)) * DI;
        size_t r1 = ((size_t)(b * KK + 1) * LL + lmap(1, l)) * DI;
        size_t r2 = ((size_t)(b * KK + 2) * LL + lmap(2, l)) * DI;
        size_t r3 = ((size_t)(b * KK + 3) * LL + lmap(3, l)) * DI;
        float v[3];
        #pragma unroll
        for (int j = 0; j < 3; ++j) {
            int c = lane + 64 * j;
            v[j] = xc[Poff + c] * sdv[j]
                 + ysb[r0 + c] + ysb[r1 + c] + ysb[r2 + c] + ysb[r3 + c];
        }
        float s = v[0] + v[1] + v[2];
        #pragma unroll
        for (int o = 32; o; o >>= 1) s += __shfl_xor(s, o);
        float mean = s * (1.f / 192.f);
        float ss = 0.f;
        #pragma unroll
        for (int j = 0; j < 3; ++j) { float dd = v[j] - mean; ss += dd * dd; }
        #pragma unroll
        for (int o = 32; o; o >>= 1) ss += __shfl_xor(ss, o);
        float rstd = rsqrtf(ss * (1.f / 192.f) + EPSN);
        #pragma unroll
        for (int j = 0; j < 3; ++j) {
            int c = lane + 64 * j;
            gs[pl][c] = ((v[j] - mean) * rstd * nwv[j] + nbv[j]) * zs[Poff + c];
        }
    }
    __syncthreads();
    int o = tid & 127;
    int pg = tid >> 7;
    if (o < DM) {
        const float* wr = Wout + (size_t)o * DI;
        float acc[16];
        #pragma unroll
        for (int p = 0; p < 16; ++p) acc[p] = 0.f;
        for (int k0 = 0; k0 < DI; k0 += 4) {
            float4 w4 = *(const float4*)(wr + k0);
            #pragma unroll
            for (int p = 0; p < 16; ++p) {
                float4 g4 = *(const float4*)(&gs[pg * 16 + p][k0]);
                acc[p] += w4.x * g4.x + w4.y * g4.y + w4.z * g4.z + w4.w * g4.w;
            }
        }
        #pragma unroll
        for (int p = 0; p < 16; ++p)
            out[(size_t)(Pbase + pg * 16 + p) * DM + o] = acc[p];
    }
}

extern "C" void kernel_launch(void* const* d_in, const int* in_sizes, int n_in,
                              void* d_out, int out_size, void* d_ws, size_t ws_size,
                              hipStream_t stream) {
    const float* x      = (const float*)d_in[0];
    const float* in_w   = (const float*)d_in[1];
    const float* conv_w = (const float*)d_in[2];
    const float* conv_b = (const float*)d_in[3];
    const float* xpw    = (const float*)d_in[4];
    const float* dtw    = (const float*)d_in[5];
    const float* A_logs = (const float*)d_in[6];
    const float* Ds     = (const float*)d_in[7];
    const float* dtb    = (const float*)d_in[8];
    const float* nw     = (const float*)d_in[9];
    const float* nb     = (const float*)d_in[10];
    const float* out_w  = (const float*)d_in[11];
    float* out = (float*)d_out;

    char* ws = (char*)d_ws;
    size_t off = 0;
    auto alloc = [&](size_t n) { float* p = (float*)(ws + off); off += n * sizeof(float); return p; };
    float* zs   = alloc((size_t)BB * LL * DI);
    float* xc   = alloc((size_t)BB * LL * DI);
    float* dts  = alloc((size_t)BB * KK * LL * RR);
    float* Bsb  = alloc((size_t)BB * KK * LL * NS);
    float* Csb  = alloc((size_t)BB * KK * LL * NS);
    float* asum = alloc((size_t)BB * KK * NCH * DI);
    float* hpp  = alloc((size_t)BB * KK * NCH * DI * NS);
    float* ysb  = alloc((size_t)BB * KK * LL * DI);
    float* xx   = ysb;   // xx is dead after k_conv; ysb written only in k_scan2 (stream-ordered)

    k_inproj<<<BB * LL / 32, 192, 0, stream>>>(x, in_w, xx, zs);
    k_conv<<<BB * LL * DI / 256, 256, 0, stream>>>(xx, conv_w, conv_b, xc);
    k_xdbl<<<BB * LL / XP, 192, 0, stream>>>(xc, xpw, dts, Bsb, Csb);
    k_scan1<<<BB * KK * NCH, 384, 0, stream>>>(xc, dts, Bsb, A_logs, dtw, dtb, asum, hpp);
    k_mid<<<(BB * KK * DI * NS) / 256, 256, 0, stream>>>(asum, A_logs, hpp);
    k_scan2<<<BB * KK * NCH, DI, 0, stream>>>(xc, dts, Bsb, Csb, A_logs, dtw, dtb, hpp, ysb);
    k_final<<<BB * LL / 32, 256, 0, stream>>>(xc, ysb, Ds, zs, nw, nb, out_w, out);
}

// Round 21
// 418.127 us; speedup vs baseline: 1.0457x; 1.0457x over previous
//
#include <hip/hip_runtime.h>
#include <hip/hip_bf16.h>
#include <math.h>

#define BB 8
#define HS 64
#define WS 64
#define LL 4096
#define DM 96
#define DI 192
#define NS 16
#define RR 6
#define KK 4
#define NCH 128
#define LC 32
#define XP 16
#define EPSN 1e-6f

typedef __attribute__((ext_vector_type(2))) float f32x2;

__device__ __forceinline__ float fsilu(float x) { return x / (1.f + __expf(-x)); }
// raw hardware transcendentals: v_exp_f32 computes 2^x, v_log_f32 computes log2(x)
__device__ __forceinline__ float rexp2(float x) {
    float r; asm("v_exp_f32 %0, %1" : "=v"(r) : "v"(x)); return r;
}
__device__ __forceinline__ float rlog2(float x) {
    float r; asm("v_log_f32 %0, %1" : "=v"(r) : "v"(x)); return r;
}
// packed f32 math (full-rate on CDNA): one instruction per 2 lanes-worth
__device__ __forceinline__ f32x2 pk_mul(f32x2 a, f32x2 b) {
    f32x2 d; asm("v_pk_mul_f32 %0, %1, %2" : "=v"(d) : "v"(a), "v"(b)); return d;
}
__device__ __forceinline__ f32x2 pk_fma(f32x2 a, f32x2 b, f32x2 c) {
    f32x2 d; asm("v_pk_fma_f32 %0, %1, %2, %3" : "=v"(d) : "v"(a), "v"(b), "v"(c)); return d;
}
// softplus(x) = ln(1+e^x) = ln2 * log2(1 + 2^(x*log2e))
__device__ __forceinline__ float fsoftplus(float x) {
    float t = rexp2(x * 1.44269504f);
    float r = 0.69314718f * rlog2(1.f + t);
    return (x > 20.f) ? x : r;
}
// spatial index l for direction k at scan step t; lmap is an involution per k,
// so it is also the scan step at which direction k visits spatial index l.
__device__ __forceinline__ int lmap(int k, int t) {
    int tt = (k >= 2) ? (LL - 1 - t) : t;
    if (k & 1) tt = ((tt & 63) << 6) | (tt >> 6);
    return tt;
}

// ---------------- K1: in_proj + silu(z) — 4 channels x 16 positions per thread ----------------
__global__ __launch_bounds__(192) void k_inproj(const float* __restrict__ x,
        const float* __restrict__ Win, float* __restrict__ xx, float* __restrict__ zs) {
    __shared__ __align__(16) float xrow[32][96];   // 12 KB
    int p0 = blockIdx.x * 32;
    int tid = threadIdx.x;
    {   // stage 32*96 floats = 768 float4, 4 per thread
        const float4* src = (const float4*)(x + (size_t)p0 * 96);
        float4* dst = (float4*)&xrow[0][0];
        #pragma unroll
        for (int e = 0; e < 4; ++e) dst[tid + e * 192] = src[tid + e * 192];
    }
    __syncthreads();
    int c = tid % 96;          // channel base: handles c, c+96 (->xx), c+192, c+288 (->z)
    int pg = tid / 96;         // position half: [pg*16, pg*16+16)
    const float4* w0 = (const float4*)(Win + (size_t)c * 96);
    const float4* w1 = (const float4*)(Win + (size_t)(c + 96) * 96);
    const float4* w2 = (const float4*)(Win + (size_t)(c + 192) * 96);
    const float4* w3 = (const float4*)(Win + (size_t)(c + 288) * 96);
    float a0v[16], a1v[16], a2v[16], a3v[16];
    #pragma unroll
    for (int p = 0; p < 16; ++p) { a0v[p] = 0.f; a1v[p] = 0.f; a2v[p] = 0.f; a3v[p] = 0.f; }
    for (int i = 0; i < 24; ++i) {
        float4 q0 = w0[i], q1 = w1[i], q2 = w2[i], q3 = w3[i];
        #pragma unroll
        for (int p = 0; p < 16; ++p) {
            float4 x4 = *(const float4*)&xrow[pg * 16 + p][i * 4];
            a0v[p] += q0.x * x4.x + q0.y * x4.y + q0.z * x4.z + q0.w * x4.w;
            a1v[p] += q1.x * x4.x + q1.y * x4.y + q1.z * x4.z + q1.w * x4.w;
            a2v[p] += q2.x * x4.x + q2.y * x4.y + q2.z * x4.z + q2.w * x4.w;
            a3v[p] += q3.x * x4.x + q3.y * x4.y + q3.z * x4.z + q3.w * x4.w;
        }
    }
    #pragma unroll
    for (int p = 0; p < 16; ++p) {
        size_t row = (size_t)(p0 + pg * 16 + p) * DI;
        xx[row + c]      = a0v[p];
        xx[row + c + 96] = a1v[p];
        zs[row + c]      = fsilu(a2v[p]);
        zs[row + c + 96] = fsilu(a3v[p]);
    }
}

// ---------------- K2: depthwise conv 3x3 + silu ----------------
__global__ __launch_bounds__(256) void k_conv(const float* __restrict__ xx,
        const float* __restrict__ cw, const float* __restrict__ cb,
        float* __restrict__ xc) {
    int idx = blockIdx.x * 256 + threadIdx.x;   // = P*192 + d
    int d = idx % DI; int P = idx / DI;
    int l = P & (LL - 1); int h = l >> 6; int w = l & 63;
    float acc = cb[d];
    #pragma unroll
    for (int i = 0; i < 3; ++i) {
        int hh = h + i - 1;
        if ((unsigned)hh < 64u) {
            #pragma unroll
            for (int j = 0; j < 3; ++j) {
                int ww = w + j - 1;
                if ((unsigned)ww < 64u)
                    acc += xx[(size_t)(P + (i - 1) * 64 + (j - 1)) * DI + d] * cw[d * 9 + i * 3 + j];
            }
        }
    }
    xc[idx] = fsilu(acc);
}

// ---------------- K3: x_dbl = xs @ xpw^T  -> dts_raw / Bs / Cs (scan order) ----------------
__global__ __launch_bounds__(192) void k_xdbl(const float* __restrict__ xc,
        const float* __restrict__ xpw, float* __restrict__ dts_raw,
        float* __restrict__ Bs, float* __restrict__ Cs) {
    __shared__ __align__(16) float xt[XP][DI];
    int tid = threadIdx.x;
    int p0 = blockIdx.x * XP;
    {
        const float4* src = (const float4*)(xc + (size_t)p0 * DI);
        float4* dst = (float4*)&xt[0][0];
        #pragma unroll
        for (int e = 0; e < XP * DI / 4 / 192; ++e) dst[tid + e * 192] = src[tid + e * 192];
    }
    __syncthreads();
    int c = tid;
    int k = c / 38, c2 = c % 38;
    const float4* w4p = (const float4*)(xpw + (size_t)c * DI);
    float acc[XP];
    #pragma unroll
    for (int p = 0; p < XP; ++p) acc[p] = 0.f;
    if (c < 152) {
        #pragma unroll 4
        for (int i = 0; i < DI / 4; ++i) {
            float4 w4 = w4p[i];
            #pragma unroll
            for (int p = 0; p < XP; ++p) {
                float4 x4 = *(const float4*)&xt[p][i * 4];
                acc[p] += w4.x * x4.x + w4.y * x4.y + w4.z * x4.z + w4.w * x4.w;
            }
        }
        #pragma unroll
        for (int p = 0; p < XP; ++p) {
            int P = p0 + p;
            int b = P >> 12; int l = P & (LL - 1);
            int lt = ((l & 63) << 6) | (l >> 6);
            int tk = (k == 0) ? l : (k == 1) ? lt : (k == 2) ? (LL - 1 - l) : (LL - 1 - lt);
            size_t it = ((size_t)(b * KK + k) * LL + tk);
            if (c2 < RR)            dts_raw[it * RR + c2] = acc[p];
            else if (c2 < RR + NS)  Bs[it * NS + (c2 - RR)] = acc[p];
            else                    Cs[it * NS + (c2 - RR - NS)] = acc[p];
        }
    }
}

// ---------------- K5a: chunked scan pass 1 (LDS-staged B/dts; chunk summaries, h_in = 0) ----------------
__global__ __launch_bounds__(192) void k_scan1(const float* __restrict__ xc,
        const float* __restrict__ dts_raw, const float* __restrict__ Bsg,
        const float* __restrict__ A_logs, const float* __restrict__ dtw,
        const float* __restrict__ dtb,
        float* __restrict__ asum_g, float* __restrict__ hpart) {
    __shared__ __align__(16) float dts_s[LC * 8];
    __shared__ __align__(16) float bs_s[LC * NS];
    int bi = blockIdx.x;
    int b = bi >> 9; int rem = bi & 511; int k = rem >> 7; int c0 = rem & 127;
    int t0 = c0 * LC;
    int d = threadIdx.x;
    size_t g0 = (size_t)(b * KK + k) * LL + t0;
    for (int e = d; e < LC * RR; e += DI) dts_s[(e / RR) * 8 + (e % RR)] = dts_raw[g0 * RR + e];
    for (int e = d; e < LC * NS; e += DI) bs_s[e] = Bsg[g0 * NS + e];
    __syncthreads();
    int kd = k * DI + d;
    f32x2 Ar2v[8];
    #pragma unroll
    for (int n2 = 0; n2 < 8; ++n2) {
        Ar2v[n2].x = -__expf(A_logs[(size_t)kd * NS + 2 * n2]) * 1.44269504f;
        Ar2v[n2].y = -__expf(A_logs[(size_t)kd * NS + 2 * n2 + 1]) * 1.44269504f;
    }
    f32x2 dw2[3];
    #pragma unroll
    for (int r = 0; r < 3; ++r) { dw2[r].x = dtw[kd * RR + 2 * r]; dw2[r].y = dtw[kd * RR + 2 * r + 1]; }
    float bias = dtb[kd];
    f32x2 h2[8];
    #pragma unroll
    for (int n2 = 0; n2 < 8; ++n2) h2[n2] = (f32x2){0.f, 0.f};
    float asum = 0.f;
    const float* xcb = xc + (size_t)b * LL * DI + d;
    float uu[4];
    #pragma unroll
    for (int j = 0; j < 4; ++j) uu[j] = xcb[(size_t)lmap(k, t0 + j) * DI];
    for (int tg = 0; tg < LC; tg += 4) {
        float un[4];
        int tb = t0 + ((tg + 4 < LC) ? (tg + 4) : tg);
        #pragma unroll
        for (int j = 0; j < 4; ++j) un[j] = xcb[(size_t)lmap(k, tb + j) * DI];
        #pragma unroll
        for (int j = 0; j < 4; ++j) {
            int t = tg + j;
            float4 q4 = *(const float4*)&dts_s[t * 8];
            float2 q2 = *(const float2*)&dts_s[t * 8 + 4];
            f32x2 a2 = pk_mul((f32x2){q4.x, q4.y}, dw2[0]);
            a2 = pk_fma((f32x2){q4.z, q4.w}, dw2[1], a2);
            a2 = pk_fma((f32x2){q2.x, q2.y}, dw2[2], a2);
            float dt = fsoftplus(bias + a2.x + a2.y);
            asum += dt;
            float dtu = dt * uu[j];
            f32x2 dt2 = {dt, dt}, dtu2 = {dtu, dtu};
            #pragma unroll
            for (int n4 = 0; n4 < 4; ++n4) {
                float4 b4 = *(const float4*)&bs_s[t * NS + n4 * 4];
                f32x2 tl = pk_mul(dt2, Ar2v[n4 * 2]);
                f32x2 th = pk_mul(dt2, Ar2v[n4 * 2 + 1]);
                f32x2 el = {rexp2(tl.x), rexp2(tl.y)};
                f32x2 eh = {rexp2(th.x), rexp2(th.y)};
                h2[n4 * 2]     = pk_fma(h2[n4 * 2],     el, pk_mul(dtu2, (f32x2){b4.x, b4.y}));
                h2[n4 * 2 + 1] = pk_fma(h2[n4 * 2 + 1], eh, pk_mul(dtu2, (f32x2){b4.z, b4.w}));
            }
        }
        #pragma unroll
        for (int j = 0; j < 4; ++j) uu[j] = un[j];
    }
    asum_g[(size_t)bi * DI + d] = asum;
    size_t base = ((size_t)bi * DI + d) * NS;
    #pragma unroll
    for (int n4 = 0; n4 < 4; ++n4) {
        float4 hv = make_float4(h2[n4 * 2].x, h2[n4 * 2].y, h2[n4 * 2 + 1].x, h2[n4 * 2 + 1].y);
        *(float4*)&hpart[base + n4 * 4] = hv;
    }
}

// ---------------- K5b: propagate chunk-boundary states (in-place hpart -> hin) ----------------
// Unroll-8 with explicit batch prefetch (r19): loads are h-independent; prefetch hides L2 latency.
__global__ __launch_bounds__(256) void k_mid(const float* __restrict__ asum_g,
        const float* __restrict__ A_logs, float* __restrict__ hpp) {
    int g = blockIdx.x * 256 + threadIdx.x;   // B*K*DI*NS threads
    int bk = g / (DI * NS);
    int rem = g % (DI * NS);
    int d = rem >> 4; int n = rem & 15;
    int k = bk & 3;
    float Ar2 = -__expf(A_logs[(size_t)(k * DI + d) * NS + n]) * 1.44269504f;
    float h = 0.f;
    size_t rowbase = (size_t)bk * NCH * DI + d;
    float as[8], hp[8];
    #pragma unroll
    for (int j = 0; j < 8; ++j) {
        size_t row = rowbase + (size_t)j * DI;
        as[j] = asum_g[row];
        hp[j] = hpp[row * NS + n];
    }
    for (int c0 = 0; c0 < NCH; c0 += 8) {
        float asn[8], hpn[8];
        if (c0 + 8 < NCH) {
            #pragma unroll
            for (int j = 0; j < 8; ++j) {
                size_t row = rowbase + (size_t)(c0 + 8 + j) * DI;
                asn[j] = asum_g[row];
                hpn[j] = hpp[row * NS + n];
            }
        } else {
            #pragma unroll
            for (int j = 0; j < 8; ++j) { asn[j] = 0.f; hpn[j] = 0.f; }
        }
        #pragma unroll
        for (int j = 0; j < 8; ++j) {
            size_t row = rowbase + (size_t)(c0 + j) * DI;
            float a = rexp2(Ar2 * as[j]);
            hpp[row * NS + n] = h;      // becomes hin for chunk c0+j
            h = a * h + hp[j];
        }
        #pragma unroll
        for (int j = 0; j < 8; ++j) { as[j] = asn[j]; hp[j] = hpn[j]; }
    }
}

// ---------------- K5c: chunked scan pass 2 (LDS-staged; streaming per-direction y) ----------------
__global__ __launch_bounds__(192) void k_scan2(const float* __restrict__ xc,
        const float* __restrict__ dts_raw, const float* __restrict__ Bsg,
        const float* __restrict__ Csg, const float* __restrict__ A_logs,
        const float* __restrict__ dtw, const float* __restrict__ dtb,
        const float* __restrict__ hinb, float* __restrict__ ysb) {
    __shared__ __align__(16) float dts_s[LC * 8];
    __shared__ __align__(16) float bs_s[LC * NS];
    __shared__ __align__(16) float cs_s[LC * NS];
    int bi = blockIdx.x;
    int b = bi >> 9; int rem = bi & 511; int k = rem >> 7; int c0 = rem & 127;
    int t0 = c0 * LC;
    int d = threadIdx.x;
    size_t g0 = (size_t)(b * KK + k) * LL + t0;
    for (int e = d; e < LC * RR; e += DI) dts_s[(e / RR) * 8 + (e % RR)] = dts_raw[g0 * RR + e];
    for (int e = d; e < LC * NS; e += DI) bs_s[e] = Bsg[g0 * NS + e];
    for (int e = d; e < LC * NS; e += DI) cs_s[e] = Csg[g0 * NS + e];
    __syncthreads();
    int kd = k * DI + d;
    f32x2 Ar2v[8];
    #pragma unroll
    for (int n2 = 0; n2 < 8; ++n2) {
        Ar2v[n2].x = -__expf(A_logs[(size_t)kd * NS + 2 * n2]) * 1.44269504f;
        Ar2v[n2].y = -__expf(A_logs[(size_t)kd * NS + 2 * n2 + 1]) * 1.44269504f;
    }
    f32x2 dw2[3];
    #pragma unroll
    for (int r = 0; r < 3; ++r) { dw2[r].x = dtw[kd * RR + 2 * r]; dw2[r].y = dtw[kd * RR + 2 * r + 1]; }
    float bias = dtb[kd];
    size_t base = ((size_t)bi * DI + d) * NS;
    f32x2 h2[8];
    #pragma unroll
    for (int n4 = 0; n4 < 4; ++n4) {
        float4 hv = *(const float4*)&hinb[base + n4 * 4];
        h2[n4 * 2]     = (f32x2){hv.x, hv.y};
        h2[n4 * 2 + 1] = (f32x2){hv.z, hv.w};
    }
    const float* xcb = xc + (size_t)b * LL * DI + d;
    float* ysw = ysb + g0 * DI + d;   // per-direction output, SCAN order (coalesced)
    float uu[4];
    #pragma unroll
    for (int j = 0; j < 4; ++j) uu[j] = xcb[(size_t)lmap(k, t0 + j) * DI];
    for (int tg = 0; tg < LC; tg += 4) {
        float un[4];
        int tb = t0 + ((tg + 4 < LC) ? (tg + 4) : tg);
        #pragma unroll
        for (int j = 0; j < 4; ++j) un[j] = xcb[(size_t)lmap(k, tb + j) * DI];
        #pragma unroll
        for (int j = 0; j < 4; ++j) {
            int t = tg + j;
            float4 q4 = *(const float4*)&dts_s[t * 8];
            float2 q2 = *(const float2*)&dts_s[t * 8 + 4];
            f32x2 a2 = pk_mul((f32x2){q4.x, q4.y}, dw2[0]);
            a2 = pk_fma((f32x2){q4.z, q4.w}, dw2[1], a2);
            a2 = pk_fma((f32x2){q2.x, q2.y}, dw2[2], a2);
            float dt = fsoftplus(bias + a2.x + a2.y);
            float dtu = dt * uu[j];
            f32x2 dt2 = {dt, dt}, dtu2 = {dtu, dtu};
            f32x2 y2 = {0.f, 0.f};
            #pragma unroll
            for (int n4 = 0; n4 < 4; ++n4) {
                float4 b4 = *(const float4*)&bs_s[t * NS + n4 * 4];
                float4 c4 = *(const float4*)&cs_s[t * NS + n4 * 4];
                f32x2 tl = pk_mul(dt2, Ar2v[n4 * 2]);
                f32x2 th = pk_mul(dt2, Ar2v[n4 * 2 + 1]);
                f32x2 el = {rexp2(tl.x), rexp2(tl.y)};
                f32x2 eh = {rexp2(th.x), rexp2(th.y)};
                h2[n4 * 2]     = pk_fma(h2[n4 * 2],     el, pk_mul(dtu2, (f32x2){b4.x, b4.y}));
                h2[n4 * 2 + 1] = pk_fma(h2[n4 * 2 + 1], eh, pk_mul(dtu2, (f32x2){b4.z, b4.w}));
                y2 = pk_fma(h2[n4 * 2],     (f32x2){c4.x, c4.y}, y2);
                y2 = pk_fma(h2[n4 * 2 + 1], (f32x2){c4.z, c4.w}, y2);
            }
            ysw[(size_t)t * DI] = y2.x + y2.y;    // plain coalesced store, no atomics
        }
        #pragma unroll
        for (int j = 0; j < 4; ++j) uu[j] = un[j];
    }
}

// ---------------- K6: 4-way merge + D-skip + LayerNorm + gate + out_proj ----------------
__global__ __launch_bounds__(256) void k_final(const float* __restrict__ xc,
        const float* __restrict__ ysb, const float* __restrict__ Ds,
        const float* __restrict__ zs, const float* __restrict__ nw,
        const float* __restrict__ nb, const float* __restrict__ Wout,
        float* __restrict__ out) {
    __shared__ __align__(16) float gs[32][DI];
    int tid = threadIdx.x;
    int wv = tid >> 6, lane = tid & 63;
    int Pbase = blockIdx.x * 32;
    float nwv[3], nbv[3], sdv[3];
    #pragma unroll
    for (int j = 0; j < 3; ++j) {
        int c = lane + 64 * j;
        nwv[j] = nw[c]; nbv[j] = nb[c];
        sdv[j] = Ds[c] + Ds[DI + c] + Ds[2 * DI + c] + Ds[3 * DI + c];
    }
    for (int pi = 0; pi < 8; ++pi) {
        int pl = wv * 8 + pi;
        int P = Pbase + pl;
        int b = P >> 12, l = P & (LL - 1);
        size_t Poff = (size_t)P * DI;
        size_t r0 = ((size_t)(b * KK + 0) * LL + lmap(0, l)) * DI;
        size_t r1 = ((size_t)(b * KK + 1) * LL + lmap(1, l)) * DI;
        size_t r2 = ((size_t)(b * KK + 2) * LL + lmap(2, l)) * DI;
        size_t r3 = ((size_t)(b * KK + 3) * LL + lmap(3, l)) * DI;
        float v[3];
        #pragma unroll
        for (int j = 0; j < 3; ++j) {
            int c = lane + 64 * j;
            v[j] = xc[Poff + c] * sdv[j]
                 + ysb[r0 + c] + ysb[r1 + c] + ysb[r2 + c] + ysb[r3 + c];
        }
        float s = v[0] + v[1] + v[2];
        #pragma unroll
        for (int o = 32; o; o >>= 1) s += __shfl_xor(s, o);
        float mean = s * (1.f / 192.f);
        float ss = 0.f;
        #pragma unroll
        for (int j = 0; j < 3; ++j) { float dd = v[j] - mean; ss += dd * dd; }
        #pragma unroll
        for (int o = 32; o; o >>= 1) ss += __shfl_xor(ss, o);
        float rstd = rsqrtf(ss * (1.f / 192.f) + EPSN);
        #pragma unroll
        for (int j = 0; j < 3; ++j) {
            int c = lane + 64 * j;
            gs[pl][c] = ((v[j] - mean) * rstd * nwv[j] + nbv[j]) * zs[Poff + c];
        }
    }
    __syncthreads();
    int o = tid & 127;
    int pg = tid >> 7;
    if (o < DM) {
        const float* wr = Wout + (size_t)o * DI;
        float acc[16];
        #pragma unroll
        for (int p = 0; p < 16; ++p) acc[p] = 0.f;
        for (int k0 = 0; k0 < DI; k0 += 4) {
            float4 w4 = *(const float4*)(wr + k0);
            #pragma unroll
            for (int p = 0; p < 16; ++p) {
                float4 g4 = *(const float4*)(&gs[pg * 16 + p][k0]);
                acc[p] += w4.x * g4.x + w4.y * g4.y + w4.z * g4.z + w4.w * g4.w;
            }
        }
        #pragma unroll
        for (int p = 0; p < 16; ++p)
            out[(size_t)(Pbase + pg * 16 + p) * DM + o] = acc[p];
    }
}

extern "C" void kernel_launch(void* const* d_in, const int* in_sizes, int n_in,
                              void* d_out, int out_size, void* d_ws, size_t ws_size,
                              hipStream_t stream) {
    const float* x      = (const float*)d_in[0];
    const float* in_w   = (const float*)d_in[1];
    const float* conv_w = (const float*)d_in[2];
    const float* conv_b = (const float*)d_in[3];
    const float* xpw    = (const float*)d_in[4];
    const float* dtw    = (const float*)d_in[5];
    const float* A_logs = (const float*)d_in[6];
    const float* Ds     = (const float*)d_in[7];
    const float* dtb    = (const float*)d_in[8];
    const float* nw     = (const float*)d_in[9];
    const float* nb     = (const float*)d_in[10];
    const float* out_w  = (const float*)d_in[11];
    float* out = (float*)d_out;

    char* ws = (char*)d_ws;
    size_t off = 0;
    auto alloc = [&](size_t n) { float* p = (float*)(ws + off); off += n * sizeof(float); return p; };
    float* zs   = alloc((size_t)BB * LL * DI);
    float* xc   = alloc((size_t)BB * LL * DI);
    float* dts  = alloc((size_t)BB * KK * LL * RR);
    float* Bsb  = alloc((size_t)BB * KK * LL * NS);
    float* Csb  = alloc((size_t)BB * KK * LL * NS);
    float* asum = alloc((size_t)BB * KK * NCH * DI);
    float* hpp  = alloc((size_t)BB * KK * NCH * DI * NS);
    float* ysb  = alloc((size_t)BB * KK * LL * DI);
    float* xx   = ysb;   // xx is dead after k_conv; ysb written only in k_scan2 (stream-ordered)

    k_inproj<<<BB * LL / 32, 192, 0, stream>>>(x, in_w, xx, zs);
    k_conv<<<BB * LL * DI / 256, 256, 0, stream>>>(xx, conv_w, conv_b, xc);
    k_xdbl<<<BB * LL / XP, 192, 0, stream>>>(xc, xpw, dts, Bsb, Csb);
    k_scan1<<<BB * KK * NCH, DI, 0, stream>>>(xc, dts, Bsb, A_logs, dtw, dtb, asum, hpp);
    k_mid<<<(BB * KK * DI * NS) / 256, 256, 0, stream>>>(asum, A_logs, hpp);
    k_scan2<<<BB * KK * NCH, DI, 0, stream>>>(xc, dts, Bsb, Csb, A_logs, dtw, dtb, hpp, ysb);
    k_final<<<BB * LL / 32, 256, 0, stream>>>(xc, ysb, Ds, zs, nw, nb, out_w, out);
}